// Round 6
// baseline (253.868 us; speedup 1.0000x reference)
//
#include <hip/hip_runtime.h>
#include <math.h>

typedef unsigned short u16;
typedef unsigned int u32;

#define INV_LN2 1.44269504088896f
#define LN2     0.693147180559945f
#define NEG2    (-14426.9504f)          // -10000 * INV_LN2
#define EPS2    (1.44269504e-4f)        // 1e-4 * INV_LN2
#define TP_OFF  ((size_t)1 << 20)

// Problem dims (fixed): B=64, T_seq=256, T_mel=2048, D=80; SSIM out = 2038 x 70

struct Ws {
  double ssim_sum;
  double dur_sum;
  double spec_part[256];
  float  mdn_val[64];
  float  mnT[256], mxT[256], mnO[256], mxO[256];
  float  A[64 * 256];       // fwd alpha at t=1023 (log2 domain)
  float  Bv[64 * 256];      // bwd beta at t=1023 (log2 domain)
  float  alpha[64 * 256];   // fallback checkpoint
};

__device__ __forceinline__ float lae2g(float a, float b, float g) {
  float m = fmaxf(a, b);
  float d = fabsf(a - b);
  return (m + g) + __builtin_amdgcn_logf(1.0f + __builtin_amdgcn_exp2f(-d));
}
__device__ __forceinline__ float lse2f(float a, float b) {
  float m = fmaxf(a, b);
  float d = fabsf(a - b);
  return m + __builtin_amdgcn_logf(1.0f + __builtin_amdgcn_exp2f(-d));
}
__device__ __forceinline__ u16 bf16rn(float f) {
  u32 u = __float_as_uint(f);
  u32 r = (u + 0x7fffu + ((u >> 16) & 1u)) >> 16;
  return (u16)r;
}

constexpr float G11[11] = {
  0.00102838f, 0.00759876f, 0.03600077f, 0.10936070f, 0.21300554f,
  0.26601172f,
  0.21300554f, 0.10936070f, 0.03600077f, 0.00759876f, 0.00102838f};

// =======================  PRIMARY (transposed) PATH  =======================

// K0: transpose logp -> tp[b][t][s] (bf16, pre-scaled by INV_LN2) || minmax || dur
__global__ __launch_bounds__(256) void tr_k0(
    const float* __restrict__ logp, const float* __restrict__ deco,
    const float* __restrict__ dect, const float* __restrict__ duro,
    const float* __restrict__ durt, const int* __restrict__ mel_lens,
    const int* __restrict__ inp_lens, Ws* __restrict__ ws,
    u16* __restrict__ tp) {
  __shared__ u16 TL[256 * 264];  // [t_local][s] stride 264 (2-way-conflict-free)
  int bid = blockIdx.x, tid = threadIdx.x;

  if (bid < 512) {  // transpose: 64 batches x 8 chunks of 256 t
    int b = bid >> 3, t0 = (bid & 7) << 8;
    const float* src = logp + (size_t)b * 256 * 2048 + t0;
    int c = tid & 63, rw = tid >> 6;
    for (int it0 = 0; it0 < 64; it0 += 8) {
      float4 vv[8];
#pragma unroll
      for (int k = 0; k < 8; ++k) {
        int s = (it0 + k) * 4 + rw;
        vv[k] = *(const float4*)(src + (size_t)s * 2048 + 4 * c);  // 1KB/row reads
      }
#pragma unroll
      for (int k = 0; k < 8; ++k) {
        int s = (it0 + k) * 4 + rw;
        u16* d = &TL[(4 * c) * 264 + s];
        d[0]       = bf16rn(vv[k].x * INV_LN2);
        d[264]     = bf16rn(vv[k].y * INV_LN2);
        d[2 * 264] = bf16rn(vv[k].z * INV_LN2);
        d[3 * 264] = bf16rn(vv[k].w * INV_LN2);
      }
    }
    __syncthreads();
    u16* dst = tp + ((size_t)b * 2048 + t0) * 256;
    for (int it0 = 0; it0 < 64; it0 += 8) {
      uint2 ww[8];
#pragma unroll
      for (int k = 0; k < 8; ++k) {
        int t = (it0 + k) * 4 + rw;
        ww[k] = *(const uint2*)&TL[t * 264 + 4 * c];
      }
#pragma unroll
      for (int k = 0; k < 8; ++k) {
        int t = (it0 + k) * 4 + rw;
        *(uint2*)(dst + (size_t)t * 256 + 4 * c) = ww[k];  // fully contiguous out
      }
    }
    return;
  }

  float (*L)[4] = (float(*)[4])TL;

  if (bid < 768) {  // min/max + spec partial
    int idx = bid - 512, b = idx >> 2, part = idx & 3;
    int len = mel_lens[b];
    int rbeg = part * 512;
    int rcnt = len - rbeg; rcnt = rcnt < 0 ? 0 : (rcnt > 512 ? 512 : rcnt);
    float mnT = __builtin_inff(), mxT = -__builtin_inff();
    float mnO = __builtin_inff(), mxO = -__builtin_inff();
    float ssum = 0.f;
    if (rcnt > 0) {
      const float4* po = (const float4*)(deco + ((size_t)(b * 2048 + rbeg)) * 80);
      const float4* pt = (const float4*)(dect + ((size_t)(b * 2048 + rbeg)) * 80);
      int n4 = rcnt * 20;
      for (int i = tid; i < n4; i += 256) {
        float4 vo = po[i], vt = pt[i];
        mnO = fminf(mnO, fminf(fminf(vo.x, vo.y), fminf(vo.z, vo.w)));
        mxO = fmaxf(mxO, fmaxf(fmaxf(vo.x, vo.y), fmaxf(vo.z, vo.w)));
        mnT = fminf(mnT, fminf(fminf(vt.x, vt.y), fminf(vt.z, vt.w)));
        mxT = fmaxf(mxT, fmaxf(fmaxf(vt.x, vt.y), fmaxf(vt.z, vt.w)));
        float dx = vo.x - vt.x, dy = vo.y - vt.y, dz = vo.z - vt.z, dw = vo.w - vt.w;
        ssum += dx * dx + dy * dy + dz * dz + dw * dw;
      }
    }
    for (int o = 32; o; o >>= 1) {
      mnT = fminf(mnT, __shfl_xor(mnT, o));
      mxT = fmaxf(mxT, __shfl_xor(mxT, o));
      mnO = fminf(mnO, __shfl_xor(mnO, o));
      mxO = fmaxf(mxO, __shfl_xor(mxO, o));
      ssum += __shfl_xor(ssum, o);
    }
    int w = tid >> 6;
    if ((tid & 63) == 0) { L[0][w] = mnT; L[1][w] = mxT; L[2][w] = mnO; L[3][w] = mxO; L[4][w] = ssum; }
    __syncthreads();
    if (tid == 0) {
      mnT = fminf(fminf(L[0][0], L[0][1]), fminf(L[0][2], L[0][3]));
      mxT = fmaxf(fmaxf(L[1][0], L[1][1]), fmaxf(L[1][2], L[1][3]));
      mnO = fminf(fminf(L[2][0], L[2][1]), fminf(L[2][2], L[2][3]));
      mxO = fmaxf(fmaxf(L[3][0], L[3][1]), fmaxf(L[3][2], L[3][3]));
      ssum = L[4][0] + L[4][1] + L[4][2] + L[4][3];
      ws->mnT[idx] = mnT; ws->mxT[idx] = mxT; ws->mnO[idx] = mnO; ws->mxO[idx] = mxO;
      ws->spec_part[idx] = (double)ssum;
    }
    return;
  }

  {  // dur MSE + zero ssim accumulator
    float ssum = 0.f;
    for (int i = tid; i < 64 * 256; i += 256) {
      int b2 = i >> 8, s2 = i & 255;
      if (s2 < inp_lens[b2]) { float d = duro[i] - durt[i]; ssum += d * d; }
    }
    for (int o = 32; o; o >>= 1) ssum += __shfl_xor(ssum, o);
    int w = tid >> 6;
    if ((tid & 63) == 0) L[4][w] = ssum;
    __syncthreads();
    if (tid == 0) {
      ws->dur_sum = (double)(L[4][0] + L[4][1] + L[4][2] + L[4][3]);
      ws->ssim_sum = 0.0;
    }
  }
}

// K1: MDN fwd (t=1..1023) || MDN bwd (t=T..1024) || SSIM conv tiles
__global__ __launch_bounds__(256) void tr_k1(
    const u16* __restrict__ tp, const float* __restrict__ deco,
    const float* __restrict__ dect, const int* __restrict__ mel_lens,
    const int* __restrict__ inp_lens, Ws* __restrict__ ws) {
  __shared__ float smemf[14704];
  int bid = blockIdx.x, tid = threadIdx.x;

  if (bid < 128) {  // MDN: single wave, contiguous reads, register double buffer
    if (tid >= 64) return;
    __builtin_amdgcn_s_setprio(1);
    const int l = tid;
    const bool isb = bid >= 64;
    const int b = isb ? bid - 64 : bid;
    const u16* tpb = tp + (size_t)b * 2048 * 256;
    const uint2* tpb2 = (const uint2*)tpb + l;  // lane base: s=4l (8B)
    uint2 GA[32], GB[32];

    auto LOADT = [&](uint2 (&R)[32], int kb) {
      const uint2* p = tpb2 + (size_t)kb * 32 * 64;
#pragma unroll
      for (int i = 0; i < 32; ++i) R[i] = p[i * 64];  // 512B/row coalesced
    };

    if (!isb) {  // forward: alpha, t = 1..1023
      float a0 = (l == 0) ? __uint_as_float((u32)tpb[0] << 16) : NEG2;
      float a1 = NEG2, a2 = NEG2, a3 = NEG2;
      auto COMPF = [&](uint2 (&R)[32], int kb) {
#pragma unroll
        for (int i = 0; i < 32; ++i) {
          if (i == 0 && kb == 0) continue;  // skip t=0 (init)
          u32 ux = R[i].x, uy = R[i].y;
          float g0 = __uint_as_float(ux << 16);
          float g1 = __uint_as_float(ux & 0xffff0000u);
          float g2 = __uint_as_float(uy << 16);
          float g3 = __uint_as_float(uy & 0xffff0000u);
          int up = __builtin_amdgcn_update_dpp(
              __float_as_int(NEG2), __float_as_int(a3), 0x138, 0xF, 0xF, false);
          float am1 = __int_as_float(up);  // lane l <- lane l-1's a3
          float n0 = lae2g(a0, am1, g0);
          float n1 = lae2g(a1, a0, g1);
          float n2 = lae2g(a2, a1, g2);
          float n3 = lae2g(a3, a2, g3);
          a0 = n0; a1 = n1; a2 = n2; a3 = n3;
        }
      };
      LOADT(GA, 0);
      for (int kb = 0; kb < 32; kb += 2) {
        LOADT(GB, kb + 1);
        COMPF(GA, kb);
        if (kb + 2 < 32) LOADT(GA, kb + 2);
        COMPF(GB, kb + 1);
      }
      *(float4*)&ws->A[b * 256 + 4 * l] = make_float4(a0, a1, a2, a3);
    } else {  // backward adjoint: beta, t = T..1024
      const int T = mel_lens[b] - 1;
      const int ss = inp_lens[b] - 1;
      float b0 = (4 * l + 0 == ss) ? 0.f : NEG2;
      float b1 = (4 * l + 1 == ss) ? 0.f : NEG2;
      float b2 = (4 * l + 2 == ss) ? 0.f : NEG2;
      float b3 = (4 * l + 3 == ss) ? 0.f : NEG2;
      auto COMPB = [&](uint2 (&R)[32], int kb) {
#pragma unroll
        for (int ii = 0; ii < 32; ++ii) {
          int i = 31 - ii;  // t descending
          if (kb * 32 + i > T) continue;
          u32 ux = R[i].x, uy = R[i].y;
          float g0 = __uint_as_float(ux << 16);
          float g1 = __uint_as_float(ux & 0xffff0000u);
          float g2 = __uint_as_float(uy << 16);
          float g3 = __uint_as_float(uy & 0xffff0000u);
          float c0 = b0 + g0, c1 = b1 + g1, c2 = b2 + g2, c3 = b3 + g3;
          int dn = __builtin_amdgcn_update_dpp(
              __float_as_int(NEG2), __float_as_int(c0), 0x130, 0xF, 0xF, false);
          float cp = __int_as_float(dn);  // lane l <- lane l+1's c0
          b0 = lse2f(c0, c1);
          b1 = lse2f(c1, c2);
          b2 = lse2f(c2, c3);
          b3 = lse2f(c3, cp);
        }
      };
      int kbT = T >> 5;
      if (kbT >= 32) {
        LOADT(GA, kbT);
        for (int kb = kbT; kb >= 32; kb -= 2) {
          bool two = (kb - 1 >= 32);
          if (two) LOADT(GB, kb - 1);
          COMPB(GA, kb);
          if (two) {
            if (kb - 2 >= 32) LOADT(GA, kb - 2);
            COMPB(GB, kb - 1);
          }
        }
      }
      *(float4*)&ws->Bv[b * 256 + 4 * l] = make_float4(b0, b1, b2, b3);
    }
    return;
  }

  // SSIM conv tile
  float* cc = smemf;
  float* R = smemf + 14700;
  int cix = bid - 128;
  int b = cix >> 6, tile = cix & 63;
  int r0 = tile * 32;
  int nrows = 2038 - r0; nrows = nrows > 32 ? 32 : nrows;
  int nin = nrows + 10;
  int len = mel_lens[b];
  float mnT = fminf(fminf(ws->mnT[4 * b], ws->mnT[4 * b + 1]), fminf(ws->mnT[4 * b + 2], ws->mnT[4 * b + 3]));
  float mxT = fmaxf(fmaxf(ws->mxT[4 * b], ws->mxT[4 * b + 1]), fmaxf(ws->mxT[4 * b + 2], ws->mxT[4 * b + 3]));
  float mnO = fminf(fminf(ws->mnO[4 * b], ws->mnO[4 * b + 1]), fminf(ws->mnO[4 * b + 2], ws->mnO[4 * b + 3]));
  float mxO = fmaxf(fmaxf(ws->mxO[4 * b], ws->mxO[4 * b + 1]), fmaxf(ws->mxO[4 * b + 2], ws->mxO[4 * b + 3]));
  if (len < 2048) { mxT = fmaxf(mxT, 0.f); mxO = fmaxf(mxO, 0.f); }
  float sT = 1.0f / (mxT - mnT + 1e-8f);
  float sO = 1.0f / (mxO - mnO + 1e-8f);
  const float* po = deco + (size_t)b * 2048 * 80;
  const float* pt = dect + (size_t)b * 2048 * 80;

  for (int p = tid; p < nin * 70; p += 256) {
    int r = p / 70, j = p - 70 * r;
    int grow = r0 + r;
    float s0 = 0, s1 = 0, s2 = 0, s3 = 0, s4 = 0;
    if (grow < len) {
      const float* ro = po + (size_t)grow * 80 + j;
      const float* rt = pt + (size_t)grow * 80 + j;
#pragma unroll
      for (int k = 0; k < 11; ++k) {
        float tn = (rt[k] - mnT) * sT;
        float on = (ro[k] - mnO) * sO;
        float g = G11[k];
        s0 = fmaf(g, tn, s0);
        s1 = fmaf(g, on, s1);
        s2 = fmaf(g * tn, tn, s2);
        s3 = fmaf(g * on, on, s3);
        s4 = fmaf(g * tn, on, s4);
      }
    }
    cc[p] = s0; cc[2940 + p] = s1; cc[2 * 2940 + p] = s2;
    cc[3 * 2940 + p] = s3; cc[4 * 2940 + p] = s4;
  }
  __syncthreads();

  float acc = 0.f;
  for (int q = tid; q < nrows * 70; q += 256) {
    int i = q / 70, j = q - 70 * i;
    float mx = 0, my = 0, xx = 0, yy = 0, xy = 0;
#pragma unroll
    for (int k = 0; k < 11; ++k) {
      float g = G11[k];
      int o = (i + k) * 70 + j;
      mx = fmaf(g, cc[o], mx);
      my = fmaf(g, cc[2940 + o], my);
      xx = fmaf(g, cc[2 * 2940 + o], xx);
      yy = fmaf(g, cc[3 * 2940 + o], yy);
      xy = fmaf(g, cc[4 * 2940 + o], xy);
    }
    float vx = xx - mx * mx, vy = yy - my * my, vxy = xy - mx * my;
    float cs = (2.f * vxy + 9e-4f) / (vx + vy + 9e-4f);
    float lum = (2.f * mx * my + 1e-4f) / (mx * mx + my * my + 1e-4f);
    acc += lum * cs;
  }
  for (int o = 32; o; o >>= 1) acc += __shfl_xor(acc, o);
  if ((tid & 63) == 0) R[tid >> 6] = acc;
  __syncthreads();
  if (tid == 0) atomicAdd(&ws->ssim_sum, (double)(R[0] + R[1] + R[2] + R[3]));
}

// K2: combine LSE(A+B) per batch + finalize scalar
__global__ __launch_bounds__(256) void tr_k2(
    const int* __restrict__ mel_lens, const int* __restrict__ inp_lens,
    Ws* __restrict__ ws, float* __restrict__ out) {
  __shared__ float MD[64];
  __shared__ double LD[4][4];
  int tid = threadIdx.x;
  {
    int b = tid >> 2, q = tid & 3;
    const float* Ab = ws->A + b * 256;
    const float* Bb = ws->Bv + b * 256;
    float mx = -3.0e38f;
    for (int j = q; j < 256; j += 4) mx = fmaxf(mx, Ab[j] + Bb[j]);
    mx = fmaxf(mx, __shfl_xor(mx, 1));
    mx = fmaxf(mx, __shfl_xor(mx, 2));
    float se = 0.f;
    for (int j = q; j < 256; j += 4)
      se += __builtin_amdgcn_exp2f(Ab[j] + Bb[j] - mx);
    se += __shfl_xor(se, 1);
    se += __shfl_xor(se, 2);
    if (q == 0)
      MD[b] = LN2 * (mx + __builtin_amdgcn_logf(se)) + (float)(mel_lens[b] - 1) * 1e-4f;
  }
  __syncthreads();
  double sp = ws->spec_part[tid];
  double md = 0.0, ml = 0.0, il = 0.0;
  if (tid < 64) {
    md = (double)MD[tid];
    ml = (double)mel_lens[tid];
    il = (double)inp_lens[tid];
  }
  for (int o = 32; o; o >>= 1) {
    sp += __shfl_xor(sp, o);
    md += __shfl_xor(md, o);
    ml += __shfl_xor(ml, o);
    il += __shfl_xor(il, o);
  }
  int w = tid >> 6;
  if ((tid & 63) == 0) { LD[w][0] = sp; LD[w][1] = md; LD[w][2] = ml; LD[w][3] = il; }
  __syncthreads();
  if (tid == 0) {
    sp = LD[0][0] + LD[1][0] + LD[2][0] + LD[3][0];
    md = LD[0][1] + LD[1][1] + LD[2][1] + LD[3][1];
    ml = LD[0][2] + LD[1][2] + LD[2][2] + LD[3][2];
    il = LD[0][3] + LD[1][3] + LD[2][3] + LD[3][3];
    double spec = sp / (ml * 80.0);
    double dur = ws->dur_sum / il;
    double mdn = -(md / 64.0) / 256.0;
    double sm = ws->ssim_sum / (64.0 * 2038.0 * 70.0);
    double sl = 1.0 - sm;
    sl = sl < 0.0 ? 0.0 : (sl > 1.0 ? 1.0 : sl);
    out[0] = (float)(spec + sl + dur + mdn);
  }
}

// =======================  FALLBACK (round-5) PATH  =======================

#define TILE 32
#define LSTR 260
#define SMEM_FLOATS (2 * TILE * LSTR)

__device__ void mdn_tiles(const float* __restrict__ logp_b, float* smemf,
                          float& a0, float& a1, float& a2, float& a3,
                          int ts, int te) {
  const int tid = threadIdx.x;
  const int kb0 = ts >> 5, kb1 = te >> 5;

  auto load_tile = [&](int kb) {
    if (tid < 64) return;
    const int ltid = tid - 64;
    float* dst = smemf + ((kb - kb0) & 1) * (TILE * LSTR);
    const int tb = kb << 5;
    float4 gl[11];
#pragma unroll
    for (int it = 0; it < 11; ++it) {
      int i = ltid + it * 192;
      if (i < 2048) {
        int s = i >> 3, e = i & 7;
        gl[it] = *(const float4*)(logp_b + (size_t)s * 2048 + tb + 4 * e);
      }
    }
#pragma unroll
    for (int it = 0; it < 11; ++it) {
      int i = ltid + it * 192;
      if (i < 2048) {
        int s = i >> 3, e = i & 7;
        float* d = dst + (4 * e) * LSTR + s;
        d[0]        = fmaf(gl[it].x, INV_LN2, EPS2);
        d[LSTR]     = fmaf(gl[it].y, INV_LN2, EPS2);
        d[2 * LSTR] = fmaf(gl[it].z, INV_LN2, EPS2);
        d[3 * LSTR] = fmaf(gl[it].w, INV_LN2, EPS2);
      }
    }
  };

  auto STEP = [&](float gx, float gy, float gz, float gw) {
    int up = __builtin_amdgcn_update_dpp(__float_as_int(NEG2),
                                         __float_as_int(a3),
                                         0x138, 0xF, 0xF, false);
    float am1 = __int_as_float(up);
    float n0 = lae2g(a0, am1, gx);
    float n1 = lae2g(a1, a0, gy);
    float n2 = lae2g(a2, a1, gz);
    float n3 = lae2g(a3, a2, gw);
    a0 = n0; a1 = n1; a2 = n2; a3 = n3;
  };

  load_tile(kb0);
  __syncthreads();
  for (int kb = kb0; kb <= kb1; ++kb) {
    if (kb + 1 <= kb1) load_tile(kb + 1);
    if (tid < 64) {
      __builtin_amdgcn_s_setprio(1);
      const float* src = smemf + ((kb - kb0) & 1) * (TILE * LSTR) + 4 * tid;
      const int tb = kb << 5;
      int t0 = ts - tb; t0 = t0 < 0 ? 0 : t0;
      int t1 = te - tb; t1 = t1 > 31 ? 31 : t1;
      if (t0 == 0 && t1 == 31) {
        float4 G[32];
#pragma unroll
        for (int i = 0; i < 32; ++i)
          G[i] = *(const float4*)(src + i * LSTR);
#pragma unroll
        for (int i = 0; i < 32; ++i)
          STEP(G[i].x, G[i].y, G[i].z, G[i].w);
      } else {
        for (int tau = t0; tau <= t1; ++tau) {
          float4 g = *(const float4*)(src + tau * LSTR);
          STEP(g.x, g.y, g.z, g.w);
        }
      }
      __builtin_amdgcn_s_setprio(0);
    }
    __syncthreads();
  }
}

__global__ __launch_bounds__(256) void altts_k1(
    const float* __restrict__ logp,
    const float* __restrict__ deco, const float* __restrict__ dect,
    const float* __restrict__ duro, const float* __restrict__ durt,
    const int* __restrict__ mel_lens, const int* __restrict__ inp_lens,
    Ws* __restrict__ ws, int split) {
  __shared__ float smemf[SMEM_FLOATS];
  int bid = blockIdx.x;
  int tid = threadIdx.x;

  if (bid < 64) {
    if (split <= 0) return;
    int b = bid;
    int T = mel_lens[b] - 1;
    const float* logp_b = logp + (size_t)b * 256 * 2048;
    float a0 = NEG2, a1 = NEG2, a2 = NEG2, a3 = NEG2;
    if (tid == 0) a0 = logp_b[0] * INV_LN2;
    int te = T < split ? T : split;
    mdn_tiles(logp_b, smemf, a0, a1, a2, a3, 1, te);
    if (tid < 64) {
      float* ck = ws->alpha + b * 256 + 4 * tid;
      ck[0] = a0; ck[1] = a1; ck[2] = a2; ck[3] = a3;
      if (T <= split) {
        int ss_ = inp_lens[b] - 1;
        if ((ss_ >> 2) == tid) {
          int e = ss_ & 3;
          float v = (e == 0) ? a0 : (e == 1) ? a1 : (e == 2) ? a2 : a3;
          ws->mdn_val[b] = v * LN2;
        }
      }
    }
    return;
  }

  float (*L)[4] = (float(*)[4])smemf;

  if (bid < 320) {
    int idx = bid - 64, b = idx >> 2, part = idx & 3;
    int len = mel_lens[b];
    int rbeg = part * 512;
    int rcnt = len - rbeg; rcnt = rcnt < 0 ? 0 : (rcnt > 512 ? 512 : rcnt);
    float mnT = __builtin_inff(), mxT = -__builtin_inff();
    float mnO = __builtin_inff(), mxO = -__builtin_inff();
    float ssum = 0.f;
    if (rcnt > 0) {
      const float4* po = (const float4*)(deco + ((size_t)(b * 2048 + rbeg)) * 80);
      const float4* pt = (const float4*)(dect + ((size_t)(b * 2048 + rbeg)) * 80);
      int n4 = rcnt * 20;
      for (int i = tid; i < n4; i += 256) {
        float4 vo = po[i], vt = pt[i];
        mnO = fminf(mnO, fminf(fminf(vo.x, vo.y), fminf(vo.z, vo.w)));
        mxO = fmaxf(mxO, fmaxf(fmaxf(vo.x, vo.y), fmaxf(vo.z, vo.w)));
        mnT = fminf(mnT, fminf(fminf(vt.x, vt.y), fminf(vt.z, vt.w)));
        mxT = fmaxf(mxT, fmaxf(fmaxf(vt.x, vt.y), fmaxf(vt.z, vt.w)));
        float dx = vo.x - vt.x, dy = vo.y - vt.y, dz = vo.z - vt.z, dw = vo.w - vt.w;
        ssum += dx * dx + dy * dy + dz * dz + dw * dw;
      }
    }
    for (int o = 32; o; o >>= 1) {
      mnT = fminf(mnT, __shfl_xor(mnT, o));
      mxT = fmaxf(mxT, __shfl_xor(mxT, o));
      mnO = fminf(mnO, __shfl_xor(mnO, o));
      mxO = fmaxf(mxO, __shfl_xor(mxO, o));
      ssum += __shfl_xor(ssum, o);
    }
    int w = tid >> 6;
    if ((tid & 63) == 0) { L[0][w] = mnT; L[1][w] = mxT; L[2][w] = mnO; L[3][w] = mxO; L[4][w] = ssum; }
    __syncthreads();
    if (tid == 0) {
      mnT = fminf(fminf(L[0][0], L[0][1]), fminf(L[0][2], L[0][3]));
      mxT = fmaxf(fmaxf(L[1][0], L[1][1]), fmaxf(L[1][2], L[1][3]));
      mnO = fminf(fminf(L[2][0], L[2][1]), fminf(L[2][2], L[2][3]));
      mxO = fmaxf(fmaxf(L[3][0], L[3][1]), fmaxf(L[3][2], L[3][3]));
      ssum = L[4][0] + L[4][1] + L[4][2] + L[4][3];
      ws->mnT[idx] = mnT; ws->mxT[idx] = mxT; ws->mnO[idx] = mnO; ws->mxO[idx] = mxO;
      ws->spec_part[idx] = (double)ssum;
    }
    return;
  }

  {
    float ssum = 0.f;
    for (int i = tid; i < 64 * 256; i += 256) {
      int b2 = i >> 8, s2 = i & 255;
      if (s2 < inp_lens[b2]) { float d = duro[i] - durt[i]; ssum += d * d; }
    }
    for (int o = 32; o; o >>= 1) ssum += __shfl_xor(ssum, o);
    int w = tid >> 6;
    if ((tid & 63) == 0) L[4][w] = ssum;
    __syncthreads();
    if (tid == 0) {
      ws->dur_sum = (double)(L[4][0] + L[4][1] + L[4][2] + L[4][3]);
      ws->ssim_sum = 0.0;
    }
  }
}

__global__ __launch_bounds__(256) void altts_k2(
    const float* __restrict__ logp,
    const float* __restrict__ deco, const float* __restrict__ dect,
    const int* __restrict__ mel_lens, const int* __restrict__ inp_lens,
    Ws* __restrict__ ws, int split) {
  __shared__ float smemf[SMEM_FLOATS];
  int bid = blockIdx.x, tid = threadIdx.x;

  if (bid < 64) {
    int b = bid;
    int T = mel_lens[b] - 1;
    if (split > 0 && T <= split) return;
    const float* logp_b = logp + (size_t)b * 256 * 2048;
    float a0 = NEG2, a1 = NEG2, a2 = NEG2, a3 = NEG2;
    int ts;
    if (split > 0) {
      if (tid < 64) {
        const float* ck = ws->alpha + b * 256 + 4 * tid;
        a0 = ck[0]; a1 = ck[1]; a2 = ck[2]; a3 = ck[3];
      }
      ts = split + 1;
    } else {
      if (tid == 0) a0 = logp_b[0] * INV_LN2;
      ts = 1;
    }
    mdn_tiles(logp_b, smemf, a0, a1, a2, a3, ts, T);
    if (tid < 64) {
      int ss_ = inp_lens[b] - 1;
      if ((ss_ >> 2) == tid) {
        int e = ss_ & 3;
        float v = (e == 0) ? a0 : (e == 1) ? a1 : (e == 2) ? a2 : a3;
        ws->mdn_val[b] = v * LN2;
      }
    }
    return;
  }

  float* cc = smemf;
  float* R = smemf + 14700;
  int cix = bid - 64;
  int b = cix >> 6, tile = cix & 63;
  int r0 = tile * 32;
  int nrows = 2038 - r0; nrows = nrows > 32 ? 32 : nrows;
  int nin = nrows + 10;
  int len = mel_lens[b];
  float mnT = fminf(fminf(ws->mnT[4 * b], ws->mnT[4 * b + 1]), fminf(ws->mnT[4 * b + 2], ws->mnT[4 * b + 3]));
  float mxT = fmaxf(fmaxf(ws->mxT[4 * b], ws->mxT[4 * b + 1]), fmaxf(ws->mxT[4 * b + 2], ws->mxT[4 * b + 3]));
  float mnO = fminf(fminf(ws->mnO[4 * b], ws->mnO[4 * b + 1]), fminf(ws->mnO[4 * b + 2], ws->mnO[4 * b + 3]));
  float mxO = fmaxf(fmaxf(ws->mxO[4 * b], ws->mxO[4 * b + 1]), fmaxf(ws->mxO[4 * b + 2], ws->mxO[4 * b + 3]));
  if (len < 2048) { mxT = fmaxf(mxT, 0.f); mxO = fmaxf(mxO, 0.f); }
  float sT = 1.0f / (mxT - mnT + 1e-8f);
  float sO = 1.0f / (mxO - mnO + 1e-8f);
  const float* po = deco + (size_t)b * 2048 * 80;
  const float* pt = dect + (size_t)b * 2048 * 80;

  for (int p = tid; p < nin * 70; p += 256) {
    int r = p / 70, j = p - 70 * r;
    int grow = r0 + r;
    float s0 = 0, s1 = 0, s2 = 0, s3 = 0, s4 = 0;
    if (grow < len) {
      const float* ro = po + (size_t)grow * 80 + j;
      const float* rt = pt + (size_t)grow * 80 + j;
#pragma unroll
      for (int k = 0; k < 11; ++k) {
        float tn = (rt[k] - mnT) * sT;
        float on = (ro[k] - mnO) * sO;
        float g = G11[k];
        s0 = fmaf(g, tn, s0);
        s1 = fmaf(g, on, s1);
        s2 = fmaf(g * tn, tn, s2);
        s3 = fmaf(g * on, on, s3);
        s4 = fmaf(g * tn, on, s4);
      }
    }
    cc[p] = s0; cc[2940 + p] = s1; cc[2 * 2940 + p] = s2;
    cc[3 * 2940 + p] = s3; cc[4 * 2940 + p] = s4;
  }
  __syncthreads();

  float acc = 0.f;
  for (int q = tid; q < nrows * 70; q += 256) {
    int i = q / 70, j = q - 70 * i;
    float mx = 0, my = 0, xx = 0, yy = 0, xy = 0;
#pragma unroll
    for (int k = 0; k < 11; ++k) {
      float g = G11[k];
      int o = (i + k) * 70 + j;
      mx = fmaf(g, cc[o], mx);
      my = fmaf(g, cc[2940 + o], my);
      xx = fmaf(g, cc[2 * 2940 + o], xx);
      yy = fmaf(g, cc[3 * 2940 + o], yy);
      xy = fmaf(g, cc[4 * 2940 + o], xy);
    }
    float vx = xx - mx * mx, vy = yy - my * my, vxy = xy - mx * my;
    float cs = (2.f * vxy + 9e-4f) / (vx + vy + 9e-4f);
    float lum = (2.f * mx * my + 1e-4f) / (mx * mx + my * my + 1e-4f);
    acc += lum * cs;
  }
  for (int o = 32; o; o >>= 1) acc += __shfl_xor(acc, o);
  if ((tid & 63) == 0) R[tid >> 6] = acc;
  __syncthreads();
  if (tid == 0) atomicAdd(&ws->ssim_sum, (double)(R[0] + R[1] + R[2] + R[3]));
}

__global__ __launch_bounds__(256) void altts_k3(
    const int* __restrict__ mel_lens, const int* __restrict__ inp_lens,
    Ws* __restrict__ ws, float* __restrict__ out) {
  __shared__ double LD[4][4];
  int tid = threadIdx.x;
  double sp = ws->spec_part[tid];
  double md = 0.0, ml = 0.0, il = 0.0;
  if (tid < 64) {
    md = (double)ws->mdn_val[tid];
    ml = (double)mel_lens[tid];
    il = (double)inp_lens[tid];
  }
  for (int o = 32; o; o >>= 1) {
    sp += __shfl_xor(sp, o);
    md += __shfl_xor(md, o);
    ml += __shfl_xor(ml, o);
    il += __shfl_xor(il, o);
  }
  int w = tid >> 6;
  if ((tid & 63) == 0) { LD[w][0] = sp; LD[w][1] = md; LD[w][2] = ml; LD[w][3] = il; }
  __syncthreads();
  if (tid == 0) {
    sp = LD[0][0] + LD[1][0] + LD[2][0] + LD[3][0];
    md = LD[0][1] + LD[1][1] + LD[2][1] + LD[3][1];
    ml = LD[0][2] + LD[1][2] + LD[2][2] + LD[3][2];
    il = LD[0][3] + LD[1][3] + LD[2][3] + LD[3][3];
    double spec = sp / (ml * 80.0);
    double dur = ws->dur_sum / il;
    double mdn = -(md / 64.0) / 256.0;
    double sm = ws->ssim_sum / (64.0 * 2038.0 * 70.0);
    double sl = 1.0 - sm;
    sl = sl < 0.0 ? 0.0 : (sl > 1.0 ? 1.0 : sl);
    out[0] = (float)(spec + sl + dur + mdn);
  }
}

extern "C" void kernel_launch(void* const* d_in, const int* in_sizes, int n_in,
                              void* d_out, int out_size, void* d_ws, size_t ws_size,
                              hipStream_t stream) {
  const float* logp = (const float*)d_in[0];
  const float* deco = (const float*)d_in[1];
  const float* dect = (const float*)d_in[2];
  const float* duro = (const float*)d_in[3];
  const float* durt = (const float*)d_in[4];
  const int* mel_lens = (const int*)d_in[5];
  const int* inp_lens = (const int*)d_in[6];
  Ws* ws = (Ws*)d_ws;
  size_t need = TP_OFF + (size_t)64 * 2048 * 256 * sizeof(u16);  // 68.1 MB
  if (ws_size >= need) {
    u16* tp = (u16*)((char*)d_ws + TP_OFF);
    hipLaunchKernelGGL(tr_k0, dim3(769), dim3(256), 0, stream,
                       logp, deco, dect, duro, durt, mel_lens, inp_lens, ws, tp);
    hipLaunchKernelGGL(tr_k1, dim3(128 + 64 * 64), dim3(256), 0, stream,
                       tp, deco, dect, mel_lens, inp_lens, ws);
    hipLaunchKernelGGL(tr_k2, dim3(1), dim3(256), 0, stream,
                       mel_lens, inp_lens, ws, (float*)d_out);
  } else {
    int split = (ws_size >= sizeof(Ws)) ? 1023 : 0;
    hipLaunchKernelGGL(altts_k1, dim3(321), dim3(256), 0, stream,
                       logp, deco, dect, duro, durt, mel_lens, inp_lens, ws, split);
    hipLaunchKernelGGL(altts_k2, dim3(64 + 64 * 64), dim3(256), 0, stream,
                       logp, deco, dect, mel_lens, inp_lens, ws, split);
    hipLaunchKernelGGL(altts_k3, dim3(1), dim3(256), 0, stream,
                       mel_lens, inp_lens, ws, (float*)d_out);
  }
}